// Round 10
// baseline (253.284 us; speedup 1.0000x reference)
//
#include <hip/hip_runtime.h>
#include <hip/hip_bf16.h>
#include <math.h>

#define N 8192
#define D 1024
#define C 1000
#define CP 1024
#define INV_T (1.0f / 0.3f)
#define SIM_SCALE (INV_T / 256.0f)   // feat_f8 = feat_n * 16 on both operands

typedef __bf16 bf16_t;
typedef bf16_t bf16x8 __attribute__((ext_vector_type(8)));
typedef float f32x4 __attribute__((ext_vector_type(4)));
typedef long v2l __attribute__((ext_vector_type(2)));

typedef __attribute__((address_space(3))) uint32_t lds_u32_t;
typedef const __attribute__((address_space(1))) uint32_t glb_u32_t;

#define ZBYTES (3 * N * 4 + 16)   // S, P, ceS, accums — zeroed by prep tail blocks
#define NZB 25                    // 25 * 4096 >= ZBYTES

// ---------------- prep: normalize rows -> feat_n (bf16) + feat_f8 (e4m3 x16),
//                  cast W -> Wp, zero accumulator region. One dispatch. -------
__global__ void prep_kernel(const float* __restrict__ feat,
                            const float* __restrict__ W,
                            float* __restrict__ norms, bf16_t* __restrict__ feat_n,
                            unsigned int* __restrict__ feat_f8,
                            bf16_t* __restrict__ Wp, char* __restrict__ zbase) {
  int g = blockIdx.x;
  int t = threadIdx.x;
  if (g < N) {
    int row = g;
    const float4* fr = (const float4*)(feat + (size_t)row * D);
    float4 x = fr[t];
    float ss = x.x * x.x + x.y * x.y + x.z * x.z + x.w * x.w;
    for (int off = 32; off; off >>= 1) ss += __shfl_down(ss, off, 64);
    __shared__ float sred[4];
    __shared__ float srn;
    int lane = t & 63, w = t >> 6;
    if (lane == 0) sred[w] = ss;
    __syncthreads();
    if (t == 0) {
      float tot = sred[0] + sred[1] + sred[2] + sred[3];
      float nrm = sqrtf(tot);
      norms[row] = nrm;
      srn = 1.0f / nrm;
    }
    __syncthreads();
    float rn = srn;
    union { bf16_t h[4]; uint2 u; } pk;
    pk.h[0] = (bf16_t)(x.x * rn);
    pk.h[1] = (bf16_t)(x.y * rn);
    pk.h[2] = (bf16_t)(x.z * rn);
    pk.h[3] = (bf16_t)(x.w * rn);
    *(uint2*)(feat_n + (size_t)row * D + t * 4) = pk.u;
    // fp8 e4m3, scaled by 16 so values sit in the normal range
    float rs = rn * 16.0f;
    unsigned int u8 = 0;
    u8 = __builtin_amdgcn_cvt_pk_fp8_f32(x.x * rs, x.y * rs, u8, false);
    u8 = __builtin_amdgcn_cvt_pk_fp8_f32(x.z * rs, x.w * rs, u8, true);
    feat_f8[(size_t)row * 256 + t] = u8;
  } else if (g < N + CP) {
    int row = g - N;
    union { bf16_t h[4]; uint2 u; } pk;
    if (row < C) {
      float4 x = ((const float4*)(W + (size_t)row * D))[t];
      pk.h[0] = (bf16_t)x.x; pk.h[1] = (bf16_t)x.y;
      pk.h[2] = (bf16_t)x.z; pk.h[3] = (bf16_t)x.w;
    } else {
      pk.h[0] = pk.h[1] = pk.h[2] = pk.h[3] = (bf16_t)0.0f;
    }
    *(uint2*)(Wp + (size_t)row * D + t * 4) = pk.u;
  } else {
    size_t off = (size_t)(g - N - CP) * 4096 + (size_t)t * 16;
    if (off < (size_t)ZBYTES) {
      int4 z = {0, 0, 0, 0};
      *(int4*)(zbase + off) = z;
    }
  }
}

// ---------------- GEMM tile geometry ----------------
#define BN 128
#define BK 64          // logits K-tile (bf16: 128 B/row)
#define BML 64         // logits M-tile (1024 blocks -> 4/CU)
#define BMS 128        // sim M/N-tile
#define BKS 128        // sim K-tile (fp8: 128 B/row) -> 16 barrier drains/block
#define NSIM 2080      // 64*65/2 upper-triangle blocks
// NOTE (R5 lesson): unified VGPR/AGPR file — never cap waves via __launch_bounds__.
// NOTE (R8 lesson): mfma_scale 32x32x64 blows the register file — stay 16x16x32.

// ------- bf16 staging: nrows x 64 bf16 (128 B/row), XOR 16B-chunk swizzle
template <int NROWS>
__device__ __forceinline__ void stage_tile_bf16(const bf16_t* __restrict__ g0,
                                                bf16_t* lds, int t, int w) {
#pragma unroll
  for (int p = 0; p < NROWS / 32; p++) {
    int chunk = p * 256 + t;
    int r = chunk >> 3;                // tile row
    int c = (chunk & 7) ^ (r & 7);     // global 16B-chunk within row
    const bf16_t* gp = g0 + (size_t)r * D + c * 8;
    bf16_t* lp = lds + (size_t)(p * 256 + w * 64) * 8;
    __builtin_amdgcn_global_load_lds((glb_u32_t*)gp, (lds_u32_t*)lp, 16, 0, 0);
  }
}

// ------- fp8 staging (sim): 128 rows x 128 B = 16 KB, 8x16B chunks per row.
// Low-2 chunk bits XOR-swizzled (R9-verified zero-conflict pattern per 64-B half).
__device__ __forceinline__ void stage_tile_f8(const unsigned char* __restrict__ g0,
                                              unsigned char* lds, int t, int w) {
#pragma unroll
  for (int p = 0; p < 4; p++) {
    int chunk = p * 256 + t;               // 0..1023
    int r = chunk >> 3;                    // tile row 0..127
    int c = ((chunk & 3) ^ ((r >> 1) & 3)) | (chunk & 4);  // swizzle low 2 bits
    const unsigned char* gp = g0 + (size_t)r * D + c * 16;
    unsigned char* lp = lds + (size_t)(p * 256 + w * 64) * 16;
    __builtin_amdgcn_global_load_lds((glb_u32_t*)gp, (lds_u32_t*)lp, 16, 0, 0);
  }
}

// ---------------- logits GEMM (bf16, 64x128 tile) + fused CE exp-sums ----------------
__launch_bounds__(256)
__global__ void logits_gemm(const bf16_t* __restrict__ A, const bf16_t* __restrict__ Wp,
                            const float* __restrict__ norms, const float* __restrict__ bias,
                            float* __restrict__ ceS, float* __restrict__ out) {
  __shared__ __align__(16) bf16_t As[BML * BK];
  __shared__ __align__(16) bf16_t Bs[BN * BK];
  int tileM = blockIdx.x * BML;
  int tileN = blockIdx.y * BN;
  int t = threadIdx.x;
  int lane = t & 63;
  int w = t >> 6;
  int wm = (w & 1) << 5;     // wave tile 32(M) x 64(N)
  int wn = (w >> 1) << 6;
  int l15 = lane & 15;
  int quad = lane >> 4;
  f32x4 acc[2][4] = {};
  const bf16_t* Abase = A + (size_t)tileM * D;
  const bf16_t* Bbase = Wp + (size_t)tileN * D;

  for (int k0 = 0; k0 < D; k0 += BK) {
    stage_tile_bf16<BML>(Abase + k0, As, t, w);
    stage_tile_bf16<BN>(Bbase + k0, Bs, t, w);
    __syncthreads();
#pragma unroll
    for (int h = 0; h < 2; h++) {
      bf16x8 af[2], bfr[4];
#pragma unroll
      for (int i = 0; i < 2; i++) {
        int ar = wm + i * 16 + l15;
        int cc = (h * 4 + quad) ^ (ar & 7);
        af[i] = *(const bf16x8*)(&As[ar * BK + cc * 8]);
      }
#pragma unroll
      for (int j = 0; j < 4; j++) {
        int br = wn + j * 16 + l15;
        int cc = (h * 4 + quad) ^ (br & 7);
        bfr[j] = *(const bf16x8*)(&Bs[br * BK + cc * 8]);
      }
#pragma unroll
      for (int i = 0; i < 2; i++)
#pragma unroll
        for (int j = 0; j < 4; j++)
          acc[i][j] = __builtin_amdgcn_mfma_f32_16x16x32_bf16(af[i], bfr[j], acc[i][j], 0, 0, 0);
    }
    __syncthreads();
  }
#pragma unroll
  for (int i = 0; i < 2; i++) {
#pragma unroll
    for (int r = 0; r < 4; r++) {
      int gr = tileM + wm + i * 16 + quad * 4 + r;
      float nrm = norms[gr];
      float esum = 0.0f;
#pragma unroll
      for (int j = 0; j < 4; j++) {
        int gc = tileN + wn + j * 16 + l15;
        if (gc < C) {
          float lg = nrm * acc[i][j][r] + bias[gc];
          out[(size_t)gr * C + gc] = lg;
          esum += __expf(lg);
        }
      }
      for (int m = 1; m < 16; m <<= 1) esum += __shfl_xor(esum, m, 64);
      if (l15 == 0) atomicAdd(&ceS[gr], esum);
    }
  }
}

// ---------------- sim GEMM (fp8 e4m3 16x16x32, BK=128): upper-triangle, fused SCL ----------------
__launch_bounds__(256)
__global__ void sim_gemm(const unsigned char* __restrict__ A8, const int* __restrict__ labels,
                         float* __restrict__ S, float* __restrict__ P) {
  __shared__ __align__(16) unsigned char As[BMS * BKS];
  __shared__ __align__(16) unsigned char Bs[BMS * BKS];
  int g = blockIdx.x;
  int t = threadIdx.x;
  int lane = t & 63;
  int w = t >> 6;
  int wm = (w & 1) << 6;
  int wn = (w >> 1) << 6;
  int l15 = lane & 15;
  int quad = lane >> 4;
  f32x4 acc[4][4] = {};

  const int nb = N / BMS;
  float fnb = (float)nb + 0.5f;
  int bi = (int)(fnb - sqrtf(fnb * fnb - 2.0f * (float)g));
  if (bi < 0) bi = 0;
#define TRI_OFF(r) ((r) * nb - (r) * ((r)-1) / 2)
  while (TRI_OFF(bi + 1) <= g) bi++;
  while (TRI_OFF(bi) > g) bi--;
  int bj = bi + (g - TRI_OFF(bi));
#undef TRI_OFF
  bi = __builtin_amdgcn_readfirstlane(bi);
  bj = __builtin_amdgcn_readfirstlane(bj);
  int tileM = bi * BMS;
  int tileN = bj * BMS;
  bool diag = (bi == bj);

  const unsigned char* Abase = A8 + (size_t)tileM * D;
  const unsigned char* Bbase = A8 + (size_t)tileN * D;

  for (int k0 = 0; k0 < D; k0 += BKS) {
    stage_tile_f8(Abase + k0, As, t, w);
    stage_tile_f8(Bbase + k0, Bs, t, w);
    __syncthreads();
    // two 64-B sub-steps; serialize to keep frag registers at 8 b128
#pragma unroll
    for (int kk = 0; kk < 2; kk++) {
      v2l af[4], bfr[4];
#pragma unroll
      for (int i = 0; i < 4; i++) {
        int ar = wm + i * 16 + l15;
        int cc = kk * 4 + (quad ^ ((ar >> 1) & 3));
        af[i] = *(const v2l*)(&As[ar * BKS + cc * 16]);
      }
#pragma unroll
      for (int j = 0; j < 4; j++) {
        int br = wn + j * 16 + l15;
        int cc = kk * 4 + (quad ^ ((br >> 1) & 3));
        bfr[j] = *(const v2l*)(&Bs[br * BKS + cc * 16]);
      }
#pragma unroll
      for (int h = 0; h < 2; h++)
#pragma unroll
        for (int i = 0; i < 4; i++)
#pragma unroll
          for (int j = 0; j < 4; j++)
            acc[i][j] = __builtin_amdgcn_mfma_f32_16x16x32_fp8_fp8(af[i][h], bfr[j][h],
                                                                   acc[i][j], 0, 0, 0);
    }
    __syncthreads();
  }

  int gcj[4], lc[4];
#pragma unroll
  for (int j = 0; j < 4; j++) {
    gcj[j] = tileN + wn + j * 16 + l15;
    lc[j] = labels[gcj[j]];
  }
  float csS[4] = {0.f, 0.f, 0.f, 0.f}, csP[4] = {0.f, 0.f, 0.f, 0.f};
#pragma unroll
  for (int i = 0; i < 4; i++) {
#pragma unroll
    for (int r = 0; r < 4; r++) {
      int gr = tileM + wm + i * 16 + quad * 4 + r;
      int lr = labels[gr];
      float ssum = 0.0f, psum = 0.0f;
#pragma unroll
      for (int j = 0; j < 4; j++) {
        float sim = acc[i][j][r] * SIM_SCALE;
        if (gcj[j] != gr) {
          float e = __expf(sim);
          float pv = (lc[j] == lr) ? sim : 0.0f;
          ssum += e;
          psum += pv;
          csS[j] += e;
          csP[j] += pv;
        }
      }
      for (int m = 1; m < 16; m <<= 1) {
        ssum += __shfl_xor(ssum, m, 64);
        psum += __shfl_xor(psum, m, 64);
      }
      if (l15 == 0) {
        atomicAdd(&S[gr], ssum);
        atomicAdd(&P[gr], psum);
      }
    }
  }
  if (!diag) {
#pragma unroll
    for (int j = 0; j < 4; j++) {
      csS[j] += __shfl_xor(csS[j], 16, 64);
      csS[j] += __shfl_xor(csS[j], 32, 64);
      csP[j] += __shfl_xor(csP[j], 16, 64);
      csP[j] += __shfl_xor(csP[j], 32, 64);
      if (quad == 0) {
        atomicAdd(&S[gcj[j]], csS[j]);
        atomicAdd(&P[gcj[j]], csP[j]);
      }
    }
  }
}

// ---------------- final: per-row terms -> accumulators; last block writes loss ----------------
__global__ void final_kernel(const float* __restrict__ S, const float* __restrict__ P,
                             const int* __restrict__ labels,
                             const float* __restrict__ ceS, float* __restrict__ out,
                             float* __restrict__ accums) {
  __shared__ int lh[1024];
  int t = threadIdx.x;
  for (int i = t; i < 1024; i += 256) lh[i] = 0;
  __syncthreads();
  for (int i = t; i < N; i += 256) atomicAdd(&lh[labels[i]], 1);
  __syncthreads();

  int i = blockIdx.x * 256 + t;  // 32 blocks x 256 = N
  int lab = labels[i];
  float cesum = logf(ceS[i]) - out[(size_t)i * C + lab];
  float lsum = 0.0f, lval = 0.0f;
  int cnt = lh[lab] - 1;
  if (cnt > 0) {
    float bl = logf(S[i]);
    lsum = -(P[i] - (float)cnt * bl) / (float)cnt;
    lval = 1.0f;
  }
  for (int off = 32; off; off >>= 1) {
    cesum += __shfl_down(cesum, off, 64);
    lsum += __shfl_down(lsum, off, 64);
    lval += __shfl_down(lval, off, 64);
  }
  __shared__ float sc[4], ss[4], sv[4];
  int lane = t & 63, w = t >> 6;
  if (lane == 0) { sc[w] = cesum; ss[w] = lsum; sv[w] = lval; }
  __syncthreads();
  if (t == 0) {
    atomicAdd(&accums[0], sc[0] + sc[1] + sc[2] + sc[3]);
    atomicAdd(&accums[1], ss[0] + ss[1] + ss[2] + ss[3]);
    atomicAdd(&accums[2], sv[0] + sv[1] + sv[2] + sv[3]);
    __threadfence();
    unsigned int prev = atomicAdd((unsigned int*)&accums[3], 1u);
    if (prev == 31) {
      float a0 = atomicAdd(&accums[0], 0.0f);
      float a1 = atomicAdd(&accums[1], 0.0f);
      float a2 = atomicAdd(&accums[2], 0.0f);
      float ce = a0 * (1.0f / (float)N);
      float scl = (a2 > 0.0f) ? a1 / a2 : 0.0f;
      out[(size_t)N * C] = 0.9f * ce + 0.1f * scl;
    }
  }
}

extern "C" void kernel_launch(void* const* d_in, const int* in_sizes, int n_in,
                              void* d_out, int out_size, void* d_ws, size_t ws_size,
                              hipStream_t stream) {
  const float* feat   = (const float*)d_in[0];
  const int*   labels = (const int*)d_in[1];
  const float* W      = (const float*)d_in[2];
  const float* b      = (const float*)d_in[3];
  float* out = (float*)d_out;  // [N*C logits, 1 loss]

  char* ws = (char*)d_ws;
  bf16_t*       feat_n  = (bf16_t*)ws;                               // 16.78 MB
  bf16_t*       Wp      = (bf16_t*)(ws + (size_t)N * D * 2);         //  2.10 MB
  unsigned int* feat_f8 = (unsigned int*)(ws + (size_t)N * D * 2 + (size_t)CP * D * 2);  // 8.39 MB
  float*  norms  = (float*)((char*)feat_f8 + (size_t)N * D);
  float*  S      = norms + N;        // zeroed region: S, P, ceS, accums
  float*  P      = S + N;
  float*  ceS    = P + N;
  float*  accums = ceS + N;          // [ce, scl_sum, scl_cnt, block_counter]

  prep_kernel<<<N + CP + NZB, 256, 0, stream>>>(feat, W, norms, feat_n, feat_f8,
                                                Wp, (char*)S);
  logits_gemm<<<dim3(N / BML, CP / BN), 256, 0, stream>>>(feat_n, Wp, norms, b, ceS, out);
  sim_gemm<<<NSIM, 256, 0, stream>>>((const unsigned char*)feat_f8, labels, S, P);
  final_kernel<<<N / 256, 256, 0, stream>>>(S, P, labels, ceS, out, accums);
}

// Round 11
// 223.699 us; speedup vs baseline: 1.1323x; 1.1323x over previous
//
#include <hip/hip_runtime.h>
#include <hip/hip_bf16.h>
#include <math.h>

#define N 8192
#define D 1024
#define C 1000
#define CP 1024
#define INV_T (1.0f / 0.3f)
#define SIM_SCALE (INV_T / 256.0f)   // feat_f8 = feat_n * 16 on both operands

typedef __bf16 bf16_t;
typedef bf16_t bf16x8 __attribute__((ext_vector_type(8)));
typedef float f32x4 __attribute__((ext_vector_type(4)));
typedef long v2l __attribute__((ext_vector_type(2)));

typedef __attribute__((address_space(3))) uint32_t lds_u32_t;
typedef const __attribute__((address_space(1))) uint32_t glb_u32_t;

#define ZBYTES (3 * N * 4 + 16)   // S, P, ceS, accums — zeroed by prep tail blocks
#define NZB 25                    // 25 * 4096 >= ZBYTES

// ---------------- prep: normalize rows -> feat_n (bf16) + feat_f8 (e4m3 x16),
//                  cast W -> Wp, zero accumulator region. One dispatch. -------
__global__ void prep_kernel(const float* __restrict__ feat,
                            const float* __restrict__ W,
                            float* __restrict__ norms, bf16_t* __restrict__ feat_n,
                            unsigned int* __restrict__ feat_f8,
                            bf16_t* __restrict__ Wp, char* __restrict__ zbase) {
  int g = blockIdx.x;
  int t = threadIdx.x;
  if (g < N) {
    int row = g;
    const float4* fr = (const float4*)(feat + (size_t)row * D);
    float4 x = fr[t];
    float ss = x.x * x.x + x.y * x.y + x.z * x.z + x.w * x.w;
    for (int off = 32; off; off >>= 1) ss += __shfl_down(ss, off, 64);
    __shared__ float sred[4];
    __shared__ float srn;
    int lane = t & 63, w = t >> 6;
    if (lane == 0) sred[w] = ss;
    __syncthreads();
    if (t == 0) {
      float tot = sred[0] + sred[1] + sred[2] + sred[3];
      float nrm = sqrtf(tot);
      norms[row] = nrm;
      srn = 1.0f / nrm;
    }
    __syncthreads();
    float rn = srn;
    union { bf16_t h[4]; uint2 u; } pk;
    pk.h[0] = (bf16_t)(x.x * rn);
    pk.h[1] = (bf16_t)(x.y * rn);
    pk.h[2] = (bf16_t)(x.z * rn);
    pk.h[3] = (bf16_t)(x.w * rn);
    *(uint2*)(feat_n + (size_t)row * D + t * 4) = pk.u;
    // fp8 e4m3, scaled by 16 so values sit in the normal range
    float rs = rn * 16.0f;
    unsigned int u8 = 0;
    u8 = __builtin_amdgcn_cvt_pk_fp8_f32(x.x * rs, x.y * rs, u8, false);
    u8 = __builtin_amdgcn_cvt_pk_fp8_f32(x.z * rs, x.w * rs, u8, true);
    feat_f8[(size_t)row * 256 + t] = u8;
  } else if (g < N + CP) {
    int row = g - N;
    union { bf16_t h[4]; uint2 u; } pk;
    if (row < C) {
      float4 x = ((const float4*)(W + (size_t)row * D))[t];
      pk.h[0] = (bf16_t)x.x; pk.h[1] = (bf16_t)x.y;
      pk.h[2] = (bf16_t)x.z; pk.h[3] = (bf16_t)x.w;
    } else {
      pk.h[0] = pk.h[1] = pk.h[2] = pk.h[3] = (bf16_t)0.0f;
    }
    *(uint2*)(Wp + (size_t)row * D + t * 4) = pk.u;
  } else {
    size_t off = (size_t)(g - N - CP) * 4096 + (size_t)t * 16;
    if (off < (size_t)ZBYTES) {
      int4 z = {0, 0, 0, 0};
      *(int4*)(zbase + off) = z;
    }
  }
}

// ---------------- GEMM tile geometry ----------------
#define BN 128
#define BK 64          // logits K-tile (bf16: 128 B/row)
#define BML 64         // logits M-tile (1024 blocks -> 4/CU)
#define BMS 128        // sim M/N-tile
#define BKS 128        // sim K-tile (fp8: 128 B/row) -> 16 barrier drains/block
#define NSIM 2080      // 64*65/2 upper-triangle blocks
// NOTE (R5 lesson): unified VGPR/AGPR file — never cap waves via __launch_bounds__.
// NOTE (R8 lesson): mfma_scale 32x32x64 blows the register file — stay 16x16x32.
// NOTE (R10 lesson): at 128-B row stride the swizzle must XOR all 3 chunk bits
// with (r&7) (R6-verified 0-conflict); 2-bit XOR leaves 2-way conflicts.

// ------- bf16 staging: nrows x 64 bf16 (128 B/row), XOR 16B-chunk swizzle
template <int NROWS>
__device__ __forceinline__ void stage_tile_bf16(const bf16_t* __restrict__ g0,
                                                bf16_t* lds, int t, int w) {
#pragma unroll
  for (int p = 0; p < NROWS / 32; p++) {
    int chunk = p * 256 + t;
    int r = chunk >> 3;                // tile row
    int c = (chunk & 7) ^ (r & 7);     // global 16B-chunk within row
    const bf16_t* gp = g0 + (size_t)r * D + c * 8;
    bf16_t* lp = lds + (size_t)(p * 256 + w * 64) * 8;
    __builtin_amdgcn_global_load_lds((glb_u32_t*)gp, (lds_u32_t*)lp, 16, 0, 0);
  }
}

// ------- fp8 staging (sim): 128 rows x 128 B = 16 KB, 8x16B chunks per row.
// LDS slot s of row r holds global chunk s ^ (r&7)  (R6-verified pattern).
__device__ __forceinline__ void stage_tile_f8(const unsigned char* __restrict__ g0,
                                              unsigned char* lds, int t, int w) {
#pragma unroll
  for (int p = 0; p < 4; p++) {
    int chunk = p * 256 + t;               // 0..1023
    int r = chunk >> 3;                    // tile row 0..127
    int c = (chunk & 7) ^ (r & 7);         // global 16B-chunk within row
    const unsigned char* gp = g0 + (size_t)r * D + c * 16;
    unsigned char* lp = lds + (size_t)(p * 256 + w * 64) * 16;
    __builtin_amdgcn_global_load_lds((glb_u32_t*)gp, (lds_u32_t*)lp, 16, 0, 0);
  }
}

// ---------------- logits GEMM (bf16, 64x128 tile) + fused CE exp-sums ----------------
__launch_bounds__(256)
__global__ void logits_gemm(const bf16_t* __restrict__ A, const bf16_t* __restrict__ Wp,
                            const float* __restrict__ norms, const float* __restrict__ bias,
                            float* __restrict__ ceS, float* __restrict__ out) {
  __shared__ __align__(16) bf16_t As[BML * BK];
  __shared__ __align__(16) bf16_t Bs[BN * BK];
  int tileM = blockIdx.x * BML;
  int tileN = blockIdx.y * BN;
  int t = threadIdx.x;
  int lane = t & 63;
  int w = t >> 6;
  int wm = (w & 1) << 5;     // wave tile 32(M) x 64(N)
  int wn = (w >> 1) << 6;
  int l15 = lane & 15;
  int quad = lane >> 4;
  f32x4 acc[2][4] = {};
  const bf16_t* Abase = A + (size_t)tileM * D;
  const bf16_t* Bbase = Wp + (size_t)tileN * D;

  for (int k0 = 0; k0 < D; k0 += BK) {
    stage_tile_bf16<BML>(Abase + k0, As, t, w);
    stage_tile_bf16<BN>(Bbase + k0, Bs, t, w);
    __syncthreads();
#pragma unroll
    for (int h = 0; h < 2; h++) {
      bf16x8 af[2], bfr[4];
#pragma unroll
      for (int i = 0; i < 2; i++) {
        int ar = wm + i * 16 + l15;
        int cc = (h * 4 + quad) ^ (ar & 7);
        af[i] = *(const bf16x8*)(&As[ar * BK + cc * 8]);
      }
#pragma unroll
      for (int j = 0; j < 4; j++) {
        int br = wn + j * 16 + l15;
        int cc = (h * 4 + quad) ^ (br & 7);
        bfr[j] = *(const bf16x8*)(&Bs[br * BK + cc * 8]);
      }
#pragma unroll
      for (int i = 0; i < 2; i++)
#pragma unroll
        for (int j = 0; j < 4; j++)
          acc[i][j] = __builtin_amdgcn_mfma_f32_16x16x32_bf16(af[i], bfr[j], acc[i][j], 0, 0, 0);
    }
    __syncthreads();
  }
#pragma unroll
  for (int i = 0; i < 2; i++) {
#pragma unroll
    for (int r = 0; r < 4; r++) {
      int gr = tileM + wm + i * 16 + quad * 4 + r;
      float nrm = norms[gr];
      float esum = 0.0f;
#pragma unroll
      for (int j = 0; j < 4; j++) {
        int gc = tileN + wn + j * 16 + l15;
        if (gc < C) {
          float lg = nrm * acc[i][j][r] + bias[gc];
          out[(size_t)gr * C + gc] = lg;
          esum += __expf(lg);
        }
      }
      for (int m = 1; m < 16; m <<= 1) esum += __shfl_xor(esum, m, 64);
      if (l15 == 0) atomicAdd(&ceS[gr], esum);
    }
  }
}

// ---------------- sim GEMM (fp8 e4m3 16x16x32, BKS=128): upper-triangle, fused SCL ----------------
// Lane reads slot (kk*4+quad) ^ (r&7) -> global chunk kk*4+quad (canonical
// k-order, consistent across A and B; any residual k-permutation cancels).
__launch_bounds__(256)
__global__ void sim_gemm(const unsigned char* __restrict__ A8, const int* __restrict__ labels,
                         float* __restrict__ S, float* __restrict__ P) {
  __shared__ __align__(16) unsigned char As[BMS * BKS];
  __shared__ __align__(16) unsigned char Bs[BMS * BKS];
  int g = blockIdx.x;
  int t = threadIdx.x;
  int lane = t & 63;
  int w = t >> 6;
  int wm = (w & 1) << 6;
  int wn = (w >> 1) << 6;
  int l15 = lane & 15;
  int quad = lane >> 4;
  f32x4 acc[4][4] = {};

  const int nb = N / BMS;
  float fnb = (float)nb + 0.5f;
  int bi = (int)(fnb - sqrtf(fnb * fnb - 2.0f * (float)g));
  if (bi < 0) bi = 0;
#define TRI_OFF(r) ((r) * nb - (r) * ((r)-1) / 2)
  while (TRI_OFF(bi + 1) <= g) bi++;
  while (TRI_OFF(bi) > g) bi--;
  int bj = bi + (g - TRI_OFF(bi));
#undef TRI_OFF
  bi = __builtin_amdgcn_readfirstlane(bi);
  bj = __builtin_amdgcn_readfirstlane(bj);
  int tileM = bi * BMS;
  int tileN = bj * BMS;
  bool diag = (bi == bj);

  const unsigned char* Abase = A8 + (size_t)tileM * D;
  const unsigned char* Bbase = A8 + (size_t)tileN * D;

  for (int k0 = 0; k0 < D; k0 += BKS) {
    stage_tile_f8(Abase + k0, As, t, w);
    stage_tile_f8(Bbase + k0, Bs, t, w);
    __syncthreads();
    // two 64-B sub-steps; serialize to keep frag registers at 8 b128
#pragma unroll
    for (int kk = 0; kk < 2; kk++) {
      v2l af[4], bfr[4];
#pragma unroll
      for (int i = 0; i < 4; i++) {
        int ar = wm + i * 16 + l15;
        int cc = (kk * 4 + quad) ^ (ar & 7);
        af[i] = *(const v2l*)(&As[ar * BKS + cc * 16]);
      }
#pragma unroll
      for (int j = 0; j < 4; j++) {
        int br = wn + j * 16 + l15;
        int cc = (kk * 4 + quad) ^ (br & 7);
        bfr[j] = *(const v2l*)(&Bs[br * BKS + cc * 16]);
      }
#pragma unroll
      for (int h = 0; h < 2; h++)
#pragma unroll
        for (int i = 0; i < 4; i++)
#pragma unroll
          for (int j = 0; j < 4; j++)
            acc[i][j] = __builtin_amdgcn_mfma_f32_16x16x32_fp8_fp8(af[i][h], bfr[j][h],
                                                                   acc[i][j], 0, 0, 0);
    }
    __syncthreads();
  }

  int gcj[4], lc[4];
#pragma unroll
  for (int j = 0; j < 4; j++) {
    gcj[j] = tileN + wn + j * 16 + l15;
    lc[j] = labels[gcj[j]];
  }
  float csS[4] = {0.f, 0.f, 0.f, 0.f}, csP[4] = {0.f, 0.f, 0.f, 0.f};
#pragma unroll
  for (int i = 0; i < 4; i++) {
#pragma unroll
    for (int r = 0; r < 4; r++) {
      int gr = tileM + wm + i * 16 + quad * 4 + r;
      int lr = labels[gr];
      float ssum = 0.0f, psum = 0.0f;
#pragma unroll
      for (int j = 0; j < 4; j++) {
        float sim = acc[i][j][r] * SIM_SCALE;
        if (gcj[j] != gr) {
          float e = __expf(sim);
          float pv = (lc[j] == lr) ? sim : 0.0f;
          ssum += e;
          psum += pv;
          csS[j] += e;
          csP[j] += pv;
        }
      }
      for (int m = 1; m < 16; m <<= 1) {
        ssum += __shfl_xor(ssum, m, 64);
        psum += __shfl_xor(psum, m, 64);
      }
      if (l15 == 0) {
        atomicAdd(&S[gr], ssum);
        atomicAdd(&P[gr], psum);
      }
    }
  }
  if (!diag) {
#pragma unroll
    for (int j = 0; j < 4; j++) {
      csS[j] += __shfl_xor(csS[j], 16, 64);
      csS[j] += __shfl_xor(csS[j], 32, 64);
      csP[j] += __shfl_xor(csP[j], 16, 64);
      csP[j] += __shfl_xor(csP[j], 32, 64);
      if (quad == 0) {
        atomicAdd(&S[gcj[j]], csS[j]);
        atomicAdd(&P[gcj[j]], csP[j]);
      }
    }
  }
}

// ---------------- final: per-row terms -> accumulators; last block writes loss ----------------
__global__ void final_kernel(const float* __restrict__ S, const float* __restrict__ P,
                             const int* __restrict__ labels,
                             const float* __restrict__ ceS, float* __restrict__ out,
                             float* __restrict__ accums) {
  __shared__ int lh[1024];
  int t = threadIdx.x;
  for (int i = t; i < 1024; i += 256) lh[i] = 0;
  __syncthreads();
  for (int i = t; i < N; i += 256) atomicAdd(&lh[labels[i]], 1);
  __syncthreads();

  int i = blockIdx.x * 256 + t;  // 32 blocks x 256 = N
  int lab = labels[i];
  float cesum = logf(ceS[i]) - out[(size_t)i * C + lab];
  float lsum = 0.0f, lval = 0.0f;
  int cnt = lh[lab] - 1;
  if (cnt > 0) {
    float bl = logf(S[i]);
    lsum = -(P[i] - (float)cnt * bl) / (float)cnt;
    lval = 1.0f;
  }
  for (int off = 32; off; off >>= 1) {
    cesum += __shfl_down(cesum, off, 64);
    lsum += __shfl_down(lsum, off, 64);
    lval += __shfl_down(lval, off, 64);
  }
  __shared__ float sc[4], ss[4], sv[4];
  int lane = t & 63, w = t >> 6;
  if (lane == 0) { sc[w] = cesum; ss[w] = lsum; sv[w] = lval; }
  __syncthreads();
  if (t == 0) {
    atomicAdd(&accums[0], sc[0] + sc[1] + sc[2] + sc[3]);
    atomicAdd(&accums[1], ss[0] + ss[1] + ss[2] + ss[3]);
    atomicAdd(&accums[2], sv[0] + sv[1] + sv[2] + sv[3]);
    __threadfence();
    unsigned int prev = atomicAdd((unsigned int*)&accums[3], 1u);
    if (prev == 31) {
      float a0 = atomicAdd(&accums[0], 0.0f);
      float a1 = atomicAdd(&accums[1], 0.0f);
      float a2 = atomicAdd(&accums[2], 0.0f);
      float ce = a0 * (1.0f / (float)N);
      float scl = (a2 > 0.0f) ? a1 / a2 : 0.0f;
      out[(size_t)N * C] = 0.9f * ce + 0.1f * scl;
    }
  }
}

extern "C" void kernel_launch(void* const* d_in, const int* in_sizes, int n_in,
                              void* d_out, int out_size, void* d_ws, size_t ws_size,
                              hipStream_t stream) {
  const float* feat   = (const float*)d_in[0];
  const int*   labels = (const int*)d_in[1];
  const float* W      = (const float*)d_in[2];
  const float* b      = (const float*)d_in[3];
  float* out = (float*)d_out;  // [N*C logits, 1 loss]

  char* ws = (char*)d_ws;
  bf16_t*       feat_n  = (bf16_t*)ws;                               // 16.78 MB
  bf16_t*       Wp      = (bf16_t*)(ws + (size_t)N * D * 2);         //  2.10 MB
  unsigned int* feat_f8 = (unsigned int*)(ws + (size_t)N * D * 2 + (size_t)CP * D * 2);  // 8.39 MB
  float*  norms  = (float*)((char*)feat_f8 + (size_t)N * D);
  float*  S      = norms + N;        // zeroed region: S, P, ceS, accums
  float*  P      = S + N;
  float*  ceS    = P + N;
  float*  accums = ceS + N;          // [ce, scl_sum, scl_cnt, block_counter]

  prep_kernel<<<N + CP + NZB, 256, 0, stream>>>(feat, W, norms, feat_n, feat_f8,
                                                Wp, (char*)S);
  logits_gemm<<<dim3(N / BML, CP / BN), 256, 0, stream>>>(feat_n, Wp, norms, b, ceS, out);
  sim_gemm<<<NSIM, 256, 0, stream>>>((const unsigned char*)feat_f8, labels, S, P);
  final_kernel<<<N / 256, 256, 0, stream>>>(S, P, labels, ceS, out, accums);
}